// Round 14
// baseline (380.682 us; speedup 1.0000x reference)
//
#include <hip/hip_runtime.h>
#include <hip/hip_bf16.h>
#include <cstdint>
#include <cstddef>

// AdaptiveSparseSelfAttention — round 22: qkv V-part 3-term ladder via a
// wave-uniform runtime branch INSIDE the single launch. R16 proved the
// numerics (V 2-level vs 3-level: identical absmax 0.01167297 in R10/R11)
// but lost ~23us to a second same-stream launch. Here `part` is block-
// uniform, so `if (part != 2)` around (a) lev-2 staging, (b) af2/bfr[.][2]
// LDS reads, (c) the 3 high-order MFMAs costs nothing (no divergence, all
// register indexing stays literal — no rule-#20 hazard). V blocks (4/12 of
// grid.x) drop 50% MFMA + 33% staging. attn / out / prep byte-identical to
// R21 (the best-of build: attn=R15 kernel, prep=fused, qkv=single launch).
//
// ws layout (98,041,856 B total when big path active):
//   Qf32 f32  [32][2048][64]                4,194,304 f  @ short 0
//   KF   bf16 [32][128 kt][3][2][64][8]    12,582,912 s  @ short 8,388,608
//   VF   bf16 [32][64 cc][4 dt][64][8]      4,194,304 s  @ short 20,971,520
//   HOS  bf16 [2 lev][8192][512]            8,388,608 s  @ short 25,165,824
//   WoS  bf16 [2 lev][512][512]               524,288 s  @ short 33,554,432
//   WqS  bf16 [3 lev][1536][512]            2,359,296 s  @ short 34,078,720
//   XS   bf16 [3 lev][8192][512]           12,582,912 s  @ short 36,438,016

#define TSEQ 2048

typedef __attribute__((ext_vector_type(8))) short bf8;
typedef __attribute__((ext_vector_type(4))) float f32x4;

#define MFMA16(A, B, C) \
  C = __builtin_amdgcn_mfma_f32_16x16x32_bf16(A, B, C, 0, 0, 0)

static __device__ __forceinline__ short f2bf(float f) {
  unsigned u = __float_as_uint(f);
  u += 0x7FFFu + ((u >> 16) & 1u);
  return (short)(u >> 16);
}
static __device__ __forceinline__ float bf2f(short s) {
  return __uint_as_float(((unsigned)(unsigned short)s) << 16);
}
static __device__ __forceinline__ unsigned pack_bf16x2(float a, float b) {
  float2 f2; f2.x = a; f2.y = b;
  __hip_bfloat162 h = __float22bfloat162_rn(f2);   // RNE, same bits as f2bf
  unsigned r;
  __builtin_memcpy(&r, &h, 4);
  return r;
}

// ---------------------------------------- prep (fallback path): Wout transpose
// W[K][N] -> out[lev][N][K], lev stride N*K (2 levels)
__global__ __launch_bounds__(256) void transpose_split(
    const float* __restrict__ W, short* __restrict__ out, int K, int N) {
  __shared__ float tile[32][129];
  const int t = threadIdx.x;
  const int nb = blockIdx.x * 128, kb = blockIdx.y * 32;
#pragma unroll
  for (int c = 0; c < 4; ++c) {
    const int flat = c * 256 + t;
    const int r = flat >> 5, nq = (flat & 31) * 4;
    const float4 g = *reinterpret_cast<const float4*>(&W[(size_t)(kb + r) * N + nb + nq]);
    tile[r][nq] = g.x; tile[r][nq + 1] = g.y;
    tile[r][nq + 2] = g.z; tile[r][nq + 3] = g.w;
  }
  __syncthreads();
  const int n = t >> 1, kh = (t & 1) * 16;
  bf8 a0, a1, b0, b1;
#pragma unroll
  for (int e = 0; e < 16; ++e) {
    const float f = tile[kh + e][n];
    const short s1 = f2bf(f);
    const short s2 = f2bf(f - bf2f(s1));
    if (e < 8) { a0[e] = s1; b0[e] = s2; }
    else       { a1[e - 8] = s1; b1[e - 8] = s2; }
  }
  const size_t o = (size_t)(nb + n) * K + kb + kh;
  const size_t ls = (size_t)N * K;
  *reinterpret_cast<bf8*>(out + o) = a0;
  *reinterpret_cast<bf8*>(out + o + 8) = a1;
  *reinterpret_cast<bf8*>(out + o + ls) = b0;
  *reinterpret_cast<bf8*>(out + o + ls + 8) = b1;
}

// ------------------------- prep (main path): all three preps in one launch.
// blocks [0,2048): xsplit3; [2048,2240): Wqkv 3-level transpose;
// [2240,2304): Wout 2-level transpose.
__global__ __launch_bounds__(256) void prep_fused(
    const float* __restrict__ X, const float* __restrict__ Wq,
    const float* __restrict__ Wo, short* __restrict__ XS,
    short* __restrict__ WqS, short* __restrict__ WoS) {
  __shared__ float tile[32][129];
  const int t = threadIdx.x;
  const int bid = blockIdx.x;
  if (bid < 2048) {
    // X[8192][512] f32 -> XS[3][8192][512] bf16
    const int i = (bid * 256 + t) * 8;
    const float4 g0 = *reinterpret_cast<const float4*>(X + i);
    const float4 g1 = *reinterpret_cast<const float4*>(X + i + 4);
    const float v[8] = {g0.x, g0.y, g0.z, g0.w, g1.x, g1.y, g1.z, g1.w};
    bf8 s1v, s2v, s3v;
#pragma unroll
    for (int e = 0; e < 8; ++e) {
      const short s1 = f2bf(v[e]);  const float r1 = v[e] - bf2f(s1);
      const short s2 = f2bf(r1);
      const short s3 = f2bf(r1 - bf2f(s2));
      s1v[e] = s1; s2v[e] = s2; s3v[e] = s3;
    }
    *reinterpret_cast<bf8*>(XS + i)           = s1v;
    *reinterpret_cast<bf8*>(XS + i + 4194304) = s2v;
    *reinterpret_cast<bf8*>(XS + i + 8388608) = s3v;
    return;
  }
  if (bid < 2240) {
    // Wq[512][1536] -> WqS[3][1536][512]
    const int b = bid - 2048;
    const int nb = (b % 12) * 128, kb = (b / 12) * 32;
    const int N = 1536, K = 512;
#pragma unroll
    for (int c = 0; c < 4; ++c) {
      const int flat = c * 256 + t;
      const int r = flat >> 5, nq = (flat & 31) * 4;
      const float4 g = *reinterpret_cast<const float4*>(&Wq[(size_t)(kb + r) * N + nb + nq]);
      tile[r][nq] = g.x; tile[r][nq + 1] = g.y;
      tile[r][nq + 2] = g.z; tile[r][nq + 3] = g.w;
    }
    __syncthreads();
    const int n = t >> 1, kh = (t & 1) * 16;
    bf8 a0, a1, b0, b1, c0, c1;
#pragma unroll
    for (int e = 0; e < 16; ++e) {
      const float f = tile[kh + e][n];
      const short s1 = f2bf(f);  const float r1 = f - bf2f(s1);
      const short s2 = f2bf(r1);
      const short s3 = f2bf(r1 - bf2f(s2));
      if (e < 8) { a0[e] = s1; b0[e] = s2; c0[e] = s3; }
      else       { a1[e - 8] = s1; b1[e - 8] = s2; c1[e - 8] = s3; }
    }
    const size_t o = (size_t)(nb + n) * K + kb + kh;
    const size_t ls = (size_t)N * K;
    *reinterpret_cast<bf8*>(WqS + o) = a0;
    *reinterpret_cast<bf8*>(WqS + o + 8) = a1;
    *reinterpret_cast<bf8*>(WqS + o + ls) = b0;
    *reinterpret_cast<bf8*>(WqS + o + ls + 8) = b1;
    *reinterpret_cast<bf8*>(WqS + o + 2 * ls) = c0;
    *reinterpret_cast<bf8*>(WqS + o + 2 * ls + 8) = c1;
    return;
  }
  {
    // Wo[512][512] -> WoS[2][512][512]
    const int b = bid - 2240;
    const int nb = (b & 3) * 128, kb = (b >> 2) * 32;
    const int N = 512, K = 512;
#pragma unroll
    for (int c = 0; c < 4; ++c) {
      const int flat = c * 256 + t;
      const int r = flat >> 5, nq = (flat & 31) * 4;
      const float4 g = *reinterpret_cast<const float4*>(&Wo[(size_t)(kb + r) * N + nb + nq]);
      tile[r][nq] = g.x; tile[r][nq + 1] = g.y;
      tile[r][nq + 2] = g.z; tile[r][nq + 3] = g.w;
    }
    __syncthreads();
    const int n = t >> 1, kh = (t & 1) * 16;
    bf8 a0, a1, b0, b1;
#pragma unroll
    for (int e = 0; e < 16; ++e) {
      const float f = tile[kh + e][n];
      const short s1 = f2bf(f);
      const short s2 = f2bf(f - bf2f(s1));
      if (e < 8) { a0[e] = s1; b0[e] = s2; }
      else       { a1[e - 8] = s1; b1[e - 8] = s2; }
    }
    const size_t o = (size_t)(nb + n) * K + kb + kh;
    const size_t ls = (size_t)N * K;
    *reinterpret_cast<bf8*>(WoS + o) = a0;
    *reinterpret_cast<bf8*>(WoS + o + 8) = a1;
    *reinterpret_cast<bf8*>(WoS + o + ls) = b0;
    *reinterpret_cast<bf8*>(WoS + o + ls + 8) = b1;
  }
}

// ---------------------------------------------------------------- K1: qkv GEMM
// Fallback path: f32 VALU (R4-proven numerics).
__global__ __launch_bounds__(256) void qkv_gemm(
    const float* __restrict__ X, const float* __restrict__ W,
    float* __restrict__ Qf32, short* __restrict__ KF, short* __restrict__ VF) {
  __shared__ float As[16][132];
  __shared__ float Bs[16][132];
  const int t = threadIdx.x;
  const int n0 = blockIdx.x * 128;
  const int m0 = blockIdx.y * 128;
  const int ti = t >> 4, tj = t & 15;
  float acc[8][8] = {};
  for (int kt = 0; kt < 512; kt += 16) {
#pragma unroll
    for (int e = 0; e < 2; ++e) {
      int idx = e * 256 + t;
      int m = idx >> 2, kq = (idx & 3) << 2;
      const float4 g = *reinterpret_cast<const float4*>(
          &X[(size_t)(m0 + m) * 512 + kt + kq]);
      As[kq + 0][m] = g.x; As[kq + 1][m] = g.y;
      As[kq + 2][m] = g.z; As[kq + 3][m] = g.w;
    }
#pragma unroll
    for (int e = 0; e < 2; ++e) {
      int idx = e * 256 + t;
      int kk = idx >> 5, n4 = (idx & 31) << 2;
      *reinterpret_cast<float4*>(&Bs[kk][n4]) =
          *reinterpret_cast<const float4*>(&W[(size_t)(kt + kk) * 1536 + n0 + n4]);
    }
    __syncthreads();
#pragma unroll
    for (int kk = 0; kk < 16; ++kk) {
      const float4 A0 = *reinterpret_cast<const float4*>(&As[kk][ti * 8]);
      const float4 A1 = *reinterpret_cast<const float4*>(&As[kk][ti * 8 + 4]);
      const float4 B0 = *reinterpret_cast<const float4*>(&Bs[kk][tj * 8]);
      const float4 B1 = *reinterpret_cast<const float4*>(&Bs[kk][tj * 8 + 4]);
      const float a[8] = {A0.x, A0.y, A0.z, A0.w, A1.x, A1.y, A1.z, A1.w};
      const float b[8] = {B0.x, B0.y, B0.z, B0.w, B1.x, B1.y, B1.z, B1.w};
#pragma unroll
      for (int ii = 0; ii < 8; ++ii)
#pragma unroll
        for (int jj = 0; jj < 8; ++jj)
          acc[ii][jj] = fmaf(a[ii], b[jj], acc[ii][jj]);
    }
    __syncthreads();
  }
  const int part = n0 >> 9;     // 0=Q 1=K 2=V
  if (part == 0) {
#pragma unroll
    for (int ii = 0; ii < 8; ++ii) {
      const int r = m0 + ti * 8 + ii;
      const int bb = r >> 11, tt = r & 2047;
#pragma unroll
      for (int jj = 0; jj < 8; ++jj) {
        const int c = (n0 & 511) + tj * 8 + jj;
        const int h = c >> 6, d = c & 63;
        Qf32[(size_t)(bb * 8 + h) * 131072 + (size_t)tt * 64 + d] =
            acc[ii][jj] * 0.125f;
      }
    }
  } else if (part == 1) {
    const int cc0 = (n0 & 511) + tj * 8;
    const int h = cc0 >> 6, d0 = cc0 & 63;
    const int kk = d0 >> 5, lg = (d0 & 31) >> 3;   // j = d&7 == jj
#pragma unroll
    for (int ii = 0; ii < 8; ++ii) {
      const int r = m0 + ti * 8 + ii;
      const int bb = r >> 11, tt = r & 2047;
      const size_t base = (size_t)(bb * 8 + h) * 393216 +
                          (size_t)(tt >> 4) * 3072 + kk * 512 +
                          ((tt & 15) + 16 * lg) * 8;
      bf8 v1, v2, v3;
#pragma unroll
      for (int jj = 0; jj < 8; ++jj) {
        const float f = acc[ii][jj];
        const short s1 = f2bf(f);  const float r1 = f - bf2f(s1);
        const short s2 = f2bf(r1);
        const short s3 = f2bf(r1 - bf2f(s2));
        v1[jj] = s1; v2[jj] = s2; v3[jj] = s3;
      }
      *reinterpret_cast<bf8*>(KF + base)        = v1;
      *reinterpret_cast<bf8*>(KF + base + 1024) = v2;
      *reinterpret_cast<bf8*>(KF + base + 2048) = v3;
    }
  } else {
    const int t0r = m0 + ti * 8;                 // 8-aligned -> j = s&7 == ii
    const int bb = t0r >> 11, tt0 = t0r & 2047;
    const int cc = tt0 >> 5, lgs = (tt0 & 31) >> 3;
#pragma unroll
    for (int jj = 0; jj < 8; ++jj) {
      const int c = (n0 & 511) + tj * 8 + jj;
      const int h = c >> 6, dd = c & 63;
      bf8 pv;
#pragma unroll
      for (int ii = 0; ii < 8; ++ii) pv[ii] = f2bf(acc[ii][jj]);
      *reinterpret_cast<bf8*>(VF + (size_t)(bb * 8 + h) * 131072 +
                              cc * 2048 + (dd >> 4) * 512 +
                              ((dd & 15) + 16 * lgs) * 8) = pv;
    }
  }
}

// ---------------------------------------- K1': qkv GEMM via MFMA (main path)
// A = XS [3][8192][512], B = WqS [3][1536][512]. Q/K blocks: 6-term ladder
// (3 levels). V blocks (part==2, wave-uniform branch): 3-term ladder —
// numerics verified identical-absmax (R10 vs R11). All register indexing
// literal; only lev-2 staging / reads / MFMAs are conditionally skipped.
__global__ __launch_bounds__(256) void qkv_mfma(
    const short* __restrict__ XS, const short* __restrict__ WqS,
    float* __restrict__ Qf32, short* __restrict__ KF, short* __restrict__ VF) {
  extern __shared__ char sm_[];
  short* As = (short*)sm_;                 // [3][128][40] bf16
  short* Bs = (short*)(sm_ + 30720);       // [3][128][40] bf16
  float* SC = (float*)sm_;                 // [128][132] f32 (after k-loop)
  const int t = threadIdx.x;
  const int w = t >> 6, lane = t & 63;
  const int lq = lane & 15, lg = lane >> 4;
  const int wr = w >> 1, wc = w & 1;
  const int n0 = blockIdx.x * 128, m0 = blockIdx.y * 128;
  const int part = n0 >> 9;                // 0=Q 1=K 2=V (block-uniform)
  const bool full = (part != 2);           // 3-level ladder?
  f32x4 acc[4][4];
#pragma unroll
  for (int i = 0; i < 4; ++i)
#pragma unroll
    for (int j2 = 0; j2 < 4; ++j2) acc[i][j2] = (f32x4){0.f, 0.f, 0.f, 0.f};
  const int sr = t >> 1, sh = (t & 1) * 16;
  for (int k0 = 0; k0 < 512; k0 += 32) {
#pragma unroll
    for (int lev = 0; lev < 2; ++lev) {
      const size_t xa = (size_t)lev * 4194304 + (size_t)(m0 + sr) * 512 + k0 + sh;
      *reinterpret_cast<bf8*>(&As[(lev * 128 + sr) * 40 + sh])     =
          *reinterpret_cast<const bf8*>(XS + xa);
      *reinterpret_cast<bf8*>(&As[(lev * 128 + sr) * 40 + sh + 8]) =
          *reinterpret_cast<const bf8*>(XS + xa + 8);
      const size_t wa = (size_t)lev * 786432 + (size_t)(n0 + sr) * 512 + k0 + sh;
      *reinterpret_cast<bf8*>(&Bs[(lev * 128 + sr) * 40 + sh])     =
          *reinterpret_cast<const bf8*>(WqS + wa);
      *reinterpret_cast<bf8*>(&Bs[(lev * 128 + sr) * 40 + sh + 8]) =
          *reinterpret_cast<const bf8*>(WqS + wa + 8);
    }
    if (full) {                            // lev-2 staging only when needed
      const size_t xa = (size_t)2 * 4194304 + (size_t)(m0 + sr) * 512 + k0 + sh;
      *reinterpret_cast<bf8*>(&As[(2 * 128 + sr) * 40 + sh])     =
          *reinterpret_cast<const bf8*>(XS + xa);
      *reinterpret_cast<bf8*>(&As[(2 * 128 + sr) * 40 + sh + 8]) =
          *reinterpret_cast<const bf8*>(XS + xa + 8);
      const size_t wa = (size_t)2 * 786432 + (size_t)(n0 + sr) * 512 + k0 + sh;
      *reinterpret_cast<bf8*>(&Bs[(2 * 128 + sr) * 40 + sh])     =
          *reinterpret_cast<const bf8*>(WqS + wa);
      *reinterpret_cast<bf8*>(&Bs[(2 * 128 + sr) * 40 + sh + 8]) =
          *reinterpret_cast<const bf8*>(WqS + wa + 8);
    }
    __syncthreads();
    bf8 bfr[4][3];
#pragma unroll
    for (int i = 0; i < 4; ++i) {
      bfr[i][0] = *reinterpret_cast<const bf8*>(
          &Bs[(0 * 128 + wc * 64 + i * 16 + lq) * 40 + lg * 8]);
      bfr[i][1] = *reinterpret_cast<const bf8*>(
          &Bs[(1 * 128 + wc * 64 + i * 16 + lq) * 40 + lg * 8]);
    }
    if (full)
#pragma unroll
      for (int i = 0; i < 4; ++i)
        bfr[i][2] = *reinterpret_cast<const bf8*>(
            &Bs[(2 * 128 + wc * 64 + i * 16 + lq) * 40 + lg * 8]);
#pragma unroll
    for (int mi = 0; mi < 4; ++mi) {
      bf8 af0 = *reinterpret_cast<const bf8*>(
          &As[(0 * 128 + wr * 64 + mi * 16 + lq) * 40 + lg * 8]);
      bf8 af1 = *reinterpret_cast<const bf8*>(
          &As[(1 * 128 + wr * 64 + mi * 16 + lq) * 40 + lg * 8]);
#pragma unroll
      for (int ni = 0; ni < 4; ++ni) {
        MFMA16(af0, bfr[ni][0], acc[mi][ni]);       // 1
        MFMA16(af0, bfr[ni][1], acc[mi][ni]);       // 2^-8
        MFMA16(af1, bfr[ni][0], acc[mi][ni]);       // 2^-8
      }
      if (full) {
        bf8 af2 = *reinterpret_cast<const bf8*>(
            &As[(2 * 128 + wr * 64 + mi * 16 + lq) * 40 + lg * 8]);
#pragma unroll
        for (int ni = 0; ni < 4; ++ni) {
          MFMA16(af1, bfr[ni][1], acc[mi][ni]);     // 2^-16
          MFMA16(af0, bfr[ni][2], acc[mi][ni]);     // 2^-16
          MFMA16(af2, bfr[ni][0], acc[mi][ni]);     // 2^-16
        }
      }
    }
    __syncthreads();
  }
  // dump accs to scratch in (m,n) order
#pragma unroll
  for (int mi = 0; mi < 4; ++mi)
#pragma unroll
    for (int ni = 0; ni < 4; ++ni)
#pragma unroll
      for (int r = 0; r < 4; ++r)
        SC[(wr * 64 + mi * 16 + lg * 4 + r) * 132 + wc * 64 + ni * 16 + lq] =
            acc[mi][ni][r];
  __syncthreads();
  // epilogue: verbatim qkv_gemm scatter, accL re-read in (ti,tj) 8x8 order
  const int ti = t >> 4, tj = t & 15;
  float accL[8][8];
#pragma unroll
  for (int ii = 0; ii < 8; ++ii) {
    const float4 c0 = *reinterpret_cast<const float4*>(&SC[(ti * 8 + ii) * 132 + tj * 8]);
    const float4 c1 = *reinterpret_cast<const float4*>(&SC[(ti * 8 + ii) * 132 + tj * 8 + 4]);
    accL[ii][0] = c0.x; accL[ii][1] = c0.y; accL[ii][2] = c0.z; accL[ii][3] = c0.w;
    accL[ii][4] = c1.x; accL[ii][5] = c1.y; accL[ii][6] = c1.z; accL[ii][7] = c1.w;
  }
  if (part == 0) {
#pragma unroll
    for (int ii = 0; ii < 8; ++ii) {
      const int r = m0 + ti * 8 + ii;
      const int bb = r >> 11, tt = r & 2047;
#pragma unroll
      for (int jj = 0; jj < 8; ++jj) {
        const int c = (n0 & 511) + tj * 8 + jj;
        const int h = c >> 6, d = c & 63;
        Qf32[(size_t)(bb * 8 + h) * 131072 + (size_t)tt * 64 + d] =
            accL[ii][jj] * 0.125f;
      }
    }
  } else if (part == 1) {
    const int cc0 = (n0 & 511) + tj * 8;
    const int h = cc0 >> 6, d0 = cc0 & 63;
    const int kk = d0 >> 5, lg2 = (d0 & 31) >> 3;   // j = d&7 == jj
#pragma unroll
    for (int ii = 0; ii < 8; ++ii) {
      const int r = m0 + ti * 8 + ii;
      const int bb = r >> 11, tt = r & 2047;
      const size_t base = (size_t)(bb * 8 + h) * 393216 +
                          (size_t)(tt >> 4) * 3072 + kk * 512 +
                          ((tt & 15) + 16 * lg2) * 8;
      bf8 v1, v2, v3;
#pragma unroll
      for (int jj = 0; jj < 8; ++jj) {
        const float f = accL[ii][jj];
        const short s1 = f2bf(f);  const float r1 = f - bf2f(s1);
        const short s2 = f2bf(r1);
        const short s3 = f2bf(r1 - bf2f(s2));
        v1[jj] = s1; v2[jj] = s2; v3[jj] = s3;
      }
      *reinterpret_cast<bf8*>(KF + base)        = v1;
      *reinterpret_cast<bf8*>(KF + base + 1024) = v2;
      *reinterpret_cast<bf8*>(KF + base + 2048) = v3;
    }
  } else {
    const int t0r = m0 + ti * 8;                 // 8-aligned -> j = s&7 == ii
    const int bb = t0r >> 11, tt0 = t0r & 2047;
    const int cc = tt0 >> 5, lgs = (tt0 & 31) >> 3;
#pragma unroll
    for (int jj = 0; jj < 8; ++jj) {
      const int c = (n0 & 511) + tj * 8 + jj;
      const int h = c >> 6, dd = c & 63;
      bf8 pv;
#pragma unroll
      for (int ii = 0; ii < 8; ++ii) pv[ii] = f2bf(accL[ii][jj]);
      *reinterpret_cast<bf8*>(VF + (size_t)(bb * 8 + h) * 131072 +
                              cc * 2048 + (dd >> 4) * 512 +
                              ((dd & 15) + 16 * lgs) * 8) = pv;
    }
  }
}

// ------------------------------------------------------------- K3: out proj GEMM
__global__ __launch_bounds__(256) void out_mfma(
    const short* __restrict__ HOS, const short* __restrict__ WoS,
    float* __restrict__ OUT) {
  __shared__ short As[2][128][40];
  __shared__ short Bs[2][128][40];
  const int t = threadIdx.x;
  const int w = t >> 6, lane = t & 63;
  const int lq = lane & 15, lg = lane >> 4;
  const int wr = w >> 1, wc = w & 1;
  const int n0 = blockIdx.x * 128, m0 = blockIdx.y * 128;
  f32x4 acc[4][4];
#pragma unroll
  for (int i = 0; i < 4; ++i)
#pragma unroll
    for (int j2 = 0; j2 < 4; ++j2) acc[i][j2] = (f32x4){0.f, 0.f, 0.f, 0.f};
  const int sm = t >> 1, sh = (t & 1) * 16;
  for (int k0 = 0; k0 < 512; k0 += 32) {
#pragma unroll
    for (int lev = 0; lev < 2; ++lev) {
      const size_t xa = (size_t)lev * 4194304 + (size_t)(m0 + sm) * 512 + k0 + sh;
      *reinterpret_cast<bf8*>(&As[lev][sm][sh])     = *reinterpret_cast<const bf8*>(HOS + xa);
      *reinterpret_cast<bf8*>(&As[lev][sm][sh + 8]) = *reinterpret_cast<const bf8*>(HOS + xa + 8);
      const size_t wa = (size_t)lev * 262144 + (size_t)(n0 + sm) * 512 + k0 + sh;
      *reinterpret_cast<bf8*>(&Bs[lev][sm][sh])     = *reinterpret_cast<const bf8*>(WoS + wa);
      *reinterpret_cast<bf8*>(&Bs[lev][sm][sh + 8]) = *reinterpret_cast<const bf8*>(WoS + wa + 8);
    }
    __syncthreads();
    bf8 af[4][2], bfr[4][2];
#pragma unroll
    for (int i = 0; i < 4; ++i)
#pragma unroll
      for (int lev = 0; lev < 2; ++lev) {
        af[i][lev]  = *reinterpret_cast<const bf8*>(&As[lev][wr * 64 + i * 16 + lq][lg * 8]);
        bfr[i][lev] = *reinterpret_cast<const bf8*>(&Bs[lev][wc * 64 + i * 16 + lq][lg * 8]);
      }
#pragma unroll
    for (int mi = 0; mi < 4; ++mi)
#pragma unroll
      for (int ni = 0; ni < 4; ++ni) {
        MFMA16(af[mi][0], bfr[ni][0], acc[mi][ni]);
        MFMA16(af[mi][0], bfr[ni][1], acc[mi][ni]);
        MFMA16(af[mi][1], bfr[ni][0], acc[mi][ni]);
      }
    __syncthreads();
  }
#pragma unroll
  for (int mi = 0; mi < 4; ++mi)
#pragma unroll
    for (int r = 0; r < 4; ++r) {
      const int m = m0 + wr * 64 + mi * 16 + lg * 4 + r;
#pragma unroll
      for (int ni = 0; ni < 4; ++ni)
        OUT[(size_t)m * 512 + n0 + wc * 64 + ni * 16 + lq] = acc[mi][ni][r];
    }
}

// ---------------------------------------------------------------- K2: attention
// R15's kernel verbatim (the fastest measured attn: 277.7 us).
// 512 threads = 8 waves; 16 distinct q-rows (row = lq); two-half logit staging
// through a 64 KB region + 8 KB park = 72 KB -> 2 blocks/CU.
__global__ __launch_bounds__(512, 4) void attn_mfma(
    const float* __restrict__ Qf32, const short* __restrict__ KF,
    const short* __restrict__ VF, const float* __restrict__ alpha,
    short* __restrict__ HOS) {
  extern __shared__ char lds[];
  const int tid = threadIdx.x;
  const int w = tid >> 6, lane = tid & 63;      // w in [0,8)
  const int lq = lane & 15, lg = lane >> 4;
  const int row = lq;                            // 16 distinct rows

  // XCD swizzle: 4096 blocks, 512/XCD = 4 bh x 128 qb
  const int flat = blockIdx.x + (int)gridDim.x * blockIdx.y;
  const int xcd = flat & 7, idx = flat >> 3;
  const int bh = xcd * 4 + (idx >> 7);
  const int qb = idx & 127;
  const int b = bh >> 3, h = bh & 7;
  const int q0 = qb * 16;

  const float gate = 1.0f / (1.0f + __expf(-alpha[h]));
  const int key = row & 7;                       // row's swizzle key

  // Q fragments: load f32 row q0+row, split 3-level in-register
  bf8 qf[3][2];
  {
    const float* qp = Qf32 + (size_t)bh * 131072 + (size_t)(q0 + row) * 64 + lg * 8;
#pragma unroll
    for (int kk = 0; kk < 2; ++kk) {
      const float4 g0 = *reinterpret_cast<const float4*>(qp + kk * 32);
      const float4 g1 = *reinterpret_cast<const float4*>(qp + kk * 32 + 4);
      const float v[8] = {g0.x, g0.y, g0.z, g0.w, g1.x, g1.y, g1.z, g1.w};
#pragma unroll
      for (int e = 0; e < 8; ++e) {
        const short s1 = f2bf(v[e]);  const float r1 = v[e] - bf2f(s1);
        const short s2 = f2bf(r1);
        const short s3 = f2bf(r1 - bf2f(s2));
        qf[0][kk][e] = s1; qf[1][kk][e] = s2; qf[2][kk][e] = s3;
      }
    }
  }

  auto ldk = [&](int t, bf8 (&dst)[3][2]) {
    const short* p = KF + (size_t)(bh * 128 + t) * 3072 + lane * 8;
    dst[0][0] = *reinterpret_cast<const bf8*>(p);
    dst[0][1] = *reinterpret_cast<const bf8*>(p + 512);
    dst[1][0] = *reinterpret_cast<const bf8*>(p + 1024);
    dst[1][1] = *reinterpret_cast<const bf8*>(p + 1536);
    dst[2][0] = *reinterpret_cast<const bf8*>(p + 2048);
    dst[2][1] = *reinterpret_cast<const bf8*>(p + 2560);
  };
  // write uses the tile's LOCAL slot (t & 63): both s-halves share the region
  auto qk = [&](bf8 (&kf)[3][2], int t) {
    f32x4 c0 = {0.f,0.f,0.f,0.f}, c1 = {0.f,0.f,0.f,0.f}, c2 = {0.f,0.f,0.f,0.f};
#pragma unroll
    for (int kk = 0; kk < 2; ++kk) {
      MFMA16(kf[0][kk], qf[0][kk], c0);   // 1
      MFMA16(kf[0][kk], qf[1][kk], c1);   // 2^-8
      MFMA16(kf[1][kk], qf[0][kk], c1);   // 2^-8
      MFMA16(kf[1][kk], qf[1][kk], c2);   // 2^-16
      MFMA16(kf[0][kk], qf[2][kk], c2);   // 2^-16
      MFMA16(kf[2][kk], qf[0][kk], c2);   // 2^-16
    }
    const f32x4 c = (c0 + c1) + c2;
    *reinterpret_cast<f32x4*>(
        lds + row * 4096 + ((((((t & 63) << 2)) + lg) ^ key) << 4)) = c;
  };

  float av[2][32];
  float lm[2] = {-3.402823466e+38f, -3.402823466e+38f};

  bf8 ka[3][2], kb[3][2];
  // ---- P1a: s-half A, tiles w+8j, j=0..7 (8 tiles/wave)
  ldk(w, ka);
#pragma unroll
  for (int j = 0; j < 8; j += 2) {
    const int t0 = w + 8 * j;
    ldk(t0 + 8, kb);
    qk(ka, t0);
    if (j + 2 < 8) ldk(t0 + 16, ka);
    qk(kb, t0 + 8);
  }
  ldk(w + 64, ka);     // half-B prologue; latency spans the next two phases
  __syncthreads();

  // ---- loadA: wave w pulls half-A logits of rows w and w+8 into registers
#pragma unroll
  for (int rr = 0; rr < 2; ++rr) {
    const char* rowb = lds + (w + 8 * rr) * 4096;
#pragma unroll
    for (int jj = 0; jj < 4; ++jj) {
      const f32x4 v = *reinterpret_cast<const f32x4*>(rowb + ((lane + 64 * jj) << 4));
#pragma unroll
      for (int e = 0; e < 4; ++e) {
        av[rr][jj * 4 + e] = v[e];
        lm[rr] = fmaxf(lm[rr], v[e]);
      }
    }
  }
  __syncthreads();

  // ---- P1b: s-half B, tiles 64 + w+8j, overwrites the same region
#pragma unroll
  for (int j = 0; j < 8; j += 2) {
    const int t0 = 64 + w + 8 * j;
    ldk(t0 + 8, kb);
    qk(ka, t0);
    if (j + 2 < 8) ldk(t0 + 16, ka);
    qk(kb, t0 + 8);
  }
  __syncthreads();

  // ---- loadB + P2 x2 rows + weights (overwrite dead logit region)
  const int dt3 = w & 3, cg = w >> 2;            // P3 assignment
  bf8 va1, vb1;
  auto ldv1 = [&](int cc, bf8& dst) {
    dst = *reinterpret_cast<const bf8*>(
        VF + (size_t)(bh * 64 + cc) * 2048 + dt3 * 512 + lane * 8);
  };
  {
#pragma unroll
    for (int rr = 0; rr < 2; ++rr) {
      const char* rowb = lds + (w + 8 * rr) * 4096;
#pragma unroll
      for (int jj = 4; jj < 8; ++jj) {
        const f32x4 v = *reinterpret_cast<const f32x4*>(
            rowb + ((lane + 64 * (jj - 4)) << 4));
#pragma unroll
        for (int e = 0; e < 4; ++e) {
          av[rr][jj * 4 + e] = v[e];
          lm[rr] = fmaxf(lm[rr], v[e]);
        }
      }
    }
    ldv1(cg * 32, va1);                          // V prefetch under P2 math
#pragma unroll
    for (int rr = 0; rr < 2; ++rr) {
      const int q = w + 8 * rr;
      const int rkey = q & 7;
      // m = global max; g0 = min of per-lane maxima -> cnt(>=g0) >= 64.
      float m = lm[rr], g0 = lm[rr];
#pragma unroll
      for (int off = 32; off; off >>= 1) {
        m = fmaxf(m, __shfl_xor(m, off));
        g0 = fminf(g0, __shfl_xor(g0, off));
      }
      // invariant: cnt(>= lo) >= 64; cnt(>= hi) < 64 (generic case)
      float lo = g0, hi = m;
      for (int it = 0; it < 64; ++it) {
        const float mid = 0.5f * (lo + hi);
        if (!(mid > lo && mid < hi)) break;      // bracket collapsed (ties)
        int cnt = 0;
#pragma unroll
        for (int j = 0; j < 32; ++j)
          cnt += (int)__popcll(__ballot(av[rr][j] >= mid));
        if (cnt >= 64) {
          lo = mid;
          if (cnt == 64) break;                  // gap hit: exactly top-64
        } else {
          hi = mid;
        }
      }
      const float thr = lo;
      float dsum = 0.f, ssum = 0.f;
#pragma unroll
      for (int j = 0; j < 32; ++j) {
        const float e = __expf(av[rr][j] - m);
        dsum += e;
        ssum += (av[rr][j] >= thr) ? e : 0.f;
      }
#pragma unroll
      for (int off = 32; off; off >>= 1) {
        dsum += __shfl_xor(dsum, off);
        ssum += __shfl_xor(ssum, off);
      }
      const float dinv = gate / dsum;
      const float sinv = (1.0f - gate) / ssum;
#pragma unroll
      for (int jj = 0; jj < 8; ++jj) {
        const int p = lane + 64 * jj;
        const int f = p ^ rkey;
        float wv[4];
#pragma unroll
        for (int e2 = 0; e2 < 4; ++e2) {
          const float a = av[rr][jj * 4 + e2];
          wv[e2] = __expf(a - m) * (dinv + ((a >= thr) ? sinv : 0.f));
        }
        uint2 pk;
        pk.x = pack_bf16x2(wv[0], wv[1]);
        pk.y = pack_bf16x2(wv[2], wv[3]);
        *reinterpret_cast<uint2*>(
            lds + q * 4096 + ((((f >> 1) ^ rkey) << 4) + ((f & 1) << 3))) = pk;
      }
    }
  }
  __syncthreads();

  // ---- P3: wave w owns d-tile dt3 over 32 s-chunks cc = cg*32 + j.
  f32x4 o = {0.f, 0.f, 0.f, 0.f};
  {
    auto pv1 = [&](bf8 vv, int cc) {
      const bf8 pa = *reinterpret_cast<const bf8*>(
          lds + row * 4096 + ((((cc << 2) + lg) ^ key) << 4));
      MFMA16(pa, vv, o);
    };
#pragma unroll
    for (int j = 0; j < 32; j += 2) {
      const int cc = cg * 32 + j;
      ldv1(cc + 1, vb1);
      pv1(va1, cc);
      if (j + 2 < 32) ldv1(cc + 2, va1);
      pv1(vb1, cc + 1);
    }
  }
  // park: wave w -> slot w (8 KB region at 64 KB)
  {
    char* pb = lds + 65536 + (w << 10);
#pragma unroll
    for (int r = 0; r < 4; ++r)
      *reinterpret_cast<float*>(pb + (((lg * 4 + r) * 16 + lq) << 2)) = o[r];
  }
  __syncthreads();
  // reduce 2 partials (waves cg*4 + dt), write HOS. 512 thr x 2 passes.
  {
#pragma unroll
    for (int p = 0; p < 2; ++p) {
      const int q = (tid >> 6) + 8 * p, d = tid & 63;
      const int dt2 = d >> 4;
      const float s =
          *reinterpret_cast<const float*>(
              lds + 65536 + (dt2 << 10) + ((q * 16 + (d & 15)) << 2)) +
          *reinterpret_cast<const float*>(
              lds + 65536 + ((4 + dt2) << 10) + ((q * 16 + (d & 15)) << 2));
      const size_t o2 = (size_t)(b * TSEQ + q0 + q) * 512 + h * 64 + d;
      const short s1 = f2bf(s);
      HOS[o2] = s1;
      HOS[o2 + 4194304] = f2bf(s - bf2f(s1));
    }
  }
}

// ------------------------------------------------------------------- launcher
extern "C" void kernel_launch(void* const* d_in, const int* in_sizes, int n_in,
                              void* d_out, int out_size, void* d_ws, size_t ws_size,
                              hipStream_t stream) {
  const float* x     = (const float*)d_in[0];
  const float* Wqkv  = (const float*)d_in[1];
  const float* Wout  = (const float*)d_in[2];
  const float* alpha = (const float*)d_in[3];
  float* out = (float*)d_out;

  float* Qf32 = (float*)d_ws;
  short* S16  = (short*)d_ws;
  short* KF   = S16 + 8388608;
  short* VF   = S16 + 20971520;
  short* HOS  = S16 + 25165824;
  short* WoS  = S16 + 33554432;
  short* WqS  = S16 + 34078720;   // 3 x 1536 x 512
  short* XSp  = S16 + 36438016;   // 3 x 8192 x 512

  const int attn_lds = 73728;     // 64 KB logits/weights + 8 KB park
  (void)hipFuncSetAttribute((const void*)attn_mfma,
                            hipFuncAttributeMaxDynamicSharedMemorySize, attn_lds);

  const bool big = ws_size >= (size_t)98041856;
  if (big) {
    prep_fused<<<2304, 256, 0, stream>>>(x, Wqkv, Wout, XSp, WqS, WoS);
    const int qkv_lds = 67584;
    (void)hipFuncSetAttribute((const void*)qkv_mfma,
                              hipFuncAttributeMaxDynamicSharedMemorySize, qkv_lds);
    qkv_mfma<<<dim3(12, 64), 256, qkv_lds, stream>>>(XSp, WqS, Qf32, KF, VF);
  } else {
    transpose_split<<<dim3(4, 16), 256, 0, stream>>>(Wout, WoS, 512, 512);
    qkv_gemm<<<dim3(12, 64), 256, 0, stream>>>(x, Wqkv, Qf32, KF, VF);
  }
  attn_mfma<<<dim3(128, 32), 512, attn_lds, stream>>>(Qf32, KF, VF, alpha, HOS);
  out_mfma<<<dim3(4, 64), 256, 0, stream>>>(HOS, WoS, out);
}

// Round 15
// 366.511 us; speedup vs baseline: 1.0387x; 1.0387x over previous
//
#include <hip/hip_runtime.h>
#include <hip/hip_bf16.h>
#include <cstdint>
#include <cstddef>

// AdaptiveSparseSelfAttention — round 23: restore R21 (best measured: 366.7us)
// after R22's qkv V-branch regression (+14us: the wave-uniform branch inside
// the K-loop broke pipelining for the majority Q/K blocks). Session ledger:
// attn at structural floor (75% issue; 5 levers measured & closed: VGPR
// expansion x3 inert, bisect interleave regressed, prefetch depth neutral,
// micro-cuts regressed, 1-block/CU variant serialization-bound). qkv: both
// work-reduction variants regressed; straight-line 6-term ladder optimal.
// 607.5 -> 366.7us (1.66x), selection bit-stable (absmax 0.01167297).
//
// ws layout (98,041,856 B total when big path active):
//   Qf32 f32  [32][2048][64]                4,194,304 f  @ short 0
//   KF   bf16 [32][128 kt][3][2][64][8]    12,582,912 s  @ short 8,388,608
//   VF   bf16 [32][64 cc][4 dt][64][8]      4,194,304 s  @ short 20,971,520
//   HOS  bf16 [2 lev][8192][512]            8,388,608 s  @ short 25,165,824
//   WoS  bf16 [2 lev][512][512]               524,288 s  @ short 33,554,432
//   WqS  bf16 [3 lev][1536][512]            2,359,296 s  @ short 34,078,720
//   XS   bf16 [3 lev][8192][512]           12,582,912 s  @ short 36,438,016

#define TSEQ 2048

typedef __attribute__((ext_vector_type(8))) short bf8;
typedef __attribute__((ext_vector_type(4))) float f32x4;

#define MFMA16(A, B, C) \
  C = __builtin_amdgcn_mfma_f32_16x16x32_bf16(A, B, C, 0, 0, 0)

static __device__ __forceinline__ short f2bf(float f) {
  unsigned u = __float_as_uint(f);
  u += 0x7FFFu + ((u >> 16) & 1u);
  return (short)(u >> 16);
}
static __device__ __forceinline__ float bf2f(short s) {
  return __uint_as_float(((unsigned)(unsigned short)s) << 16);
}
static __device__ __forceinline__ unsigned pack_bf16x2(float a, float b) {
  float2 f2; f2.x = a; f2.y = b;
  __hip_bfloat162 h = __float22bfloat162_rn(f2);   // RNE, same bits as f2bf
  unsigned r;
  __builtin_memcpy(&r, &h, 4);
  return r;
}

// ---------------------------------------- prep (fallback path): Wout transpose
// W[K][N] -> out[lev][N][K], lev stride N*K (2 levels)
__global__ __launch_bounds__(256) void transpose_split(
    const float* __restrict__ W, short* __restrict__ out, int K, int N) {
  __shared__ float tile[32][129];
  const int t = threadIdx.x;
  const int nb = blockIdx.x * 128, kb = blockIdx.y * 32;
#pragma unroll
  for (int c = 0; c < 4; ++c) {
    const int flat = c * 256 + t;
    const int r = flat >> 5, nq = (flat & 31) * 4;
    const float4 g = *reinterpret_cast<const float4*>(&W[(size_t)(kb + r) * N + nb + nq]);
    tile[r][nq] = g.x; tile[r][nq + 1] = g.y;
    tile[r][nq + 2] = g.z; tile[r][nq + 3] = g.w;
  }
  __syncthreads();
  const int n = t >> 1, kh = (t & 1) * 16;
  bf8 a0, a1, b0, b1;
#pragma unroll
  for (int e = 0; e < 16; ++e) {
    const float f = tile[kh + e][n];
    const short s1 = f2bf(f);
    const short s2 = f2bf(f - bf2f(s1));
    if (e < 8) { a0[e] = s1; b0[e] = s2; }
    else       { a1[e - 8] = s1; b1[e - 8] = s2; }
  }
  const size_t o = (size_t)(nb + n) * K + kb + kh;
  const size_t ls = (size_t)N * K;
  *reinterpret_cast<bf8*>(out + o) = a0;
  *reinterpret_cast<bf8*>(out + o + 8) = a1;
  *reinterpret_cast<bf8*>(out + o + ls) = b0;
  *reinterpret_cast<bf8*>(out + o + ls + 8) = b1;
}

// ------------------------- prep (main path): all three preps in one launch.
// blocks [0,2048): xsplit3; [2048,2240): Wqkv 3-level transpose;
// [2240,2304): Wout 2-level transpose.
__global__ __launch_bounds__(256) void prep_fused(
    const float* __restrict__ X, const float* __restrict__ Wq,
    const float* __restrict__ Wo, short* __restrict__ XS,
    short* __restrict__ WqS, short* __restrict__ WoS) {
  __shared__ float tile[32][129];
  const int t = threadIdx.x;
  const int bid = blockIdx.x;
  if (bid < 2048) {
    // X[8192][512] f32 -> XS[3][8192][512] bf16
    const int i = (bid * 256 + t) * 8;
    const float4 g0 = *reinterpret_cast<const float4*>(X + i);
    const float4 g1 = *reinterpret_cast<const float4*>(X + i + 4);
    const float v[8] = {g0.x, g0.y, g0.z, g0.w, g1.x, g1.y, g1.z, g1.w};
    bf8 s1v, s2v, s3v;
#pragma unroll
    for (int e = 0; e < 8; ++e) {
      const short s1 = f2bf(v[e]);  const float r1 = v[e] - bf2f(s1);
      const short s2 = f2bf(r1);
      const short s3 = f2bf(r1 - bf2f(s2));
      s1v[e] = s1; s2v[e] = s2; s3v[e] = s3;
    }
    *reinterpret_cast<bf8*>(XS + i)           = s1v;
    *reinterpret_cast<bf8*>(XS + i + 4194304) = s2v;
    *reinterpret_cast<bf8*>(XS + i + 8388608) = s3v;
    return;
  }
  if (bid < 2240) {
    // Wq[512][1536] -> WqS[3][1536][512]
    const int b = bid - 2048;
    const int nb = (b % 12) * 128, kb = (b / 12) * 32;
    const int N = 1536, K = 512;
#pragma unroll
    for (int c = 0; c < 4; ++c) {
      const int flat = c * 256 + t;
      const int r = flat >> 5, nq = (flat & 31) * 4;
      const float4 g = *reinterpret_cast<const float4*>(&Wq[(size_t)(kb + r) * N + nb + nq]);
      tile[r][nq] = g.x; tile[r][nq + 1] = g.y;
      tile[r][nq + 2] = g.z; tile[r][nq + 3] = g.w;
    }
    __syncthreads();
    const int n = t >> 1, kh = (t & 1) * 16;
    bf8 a0, a1, b0, b1, c0, c1;
#pragma unroll
    for (int e = 0; e < 16; ++e) {
      const float f = tile[kh + e][n];
      const short s1 = f2bf(f);  const float r1 = f - bf2f(s1);
      const short s2 = f2bf(r1);
      const short s3 = f2bf(r1 - bf2f(s2));
      if (e < 8) { a0[e] = s1; b0[e] = s2; c0[e] = s3; }
      else       { a1[e - 8] = s1; b1[e - 8] = s2; c1[e - 8] = s3; }
    }
    const size_t o = (size_t)(nb + n) * K + kb + kh;
    const size_t ls = (size_t)N * K;
    *reinterpret_cast<bf8*>(WqS + o) = a0;
    *reinterpret_cast<bf8*>(WqS + o + 8) = a1;
    *reinterpret_cast<bf8*>(WqS + o + ls) = b0;
    *reinterpret_cast<bf8*>(WqS + o + ls + 8) = b1;
    *reinterpret_cast<bf8*>(WqS + o + 2 * ls) = c0;
    *reinterpret_cast<bf8*>(WqS + o + 2 * ls + 8) = c1;
    return;
  }
  {
    // Wo[512][512] -> WoS[2][512][512]
    const int b = bid - 2240;
    const int nb = (b & 3) * 128, kb = (b >> 2) * 32;
    const int N = 512, K = 512;
#pragma unroll
    for (int c = 0; c < 4; ++c) {
      const int flat = c * 256 + t;
      const int r = flat >> 5, nq = (flat & 31) * 4;
      const float4 g = *reinterpret_cast<const float4*>(&Wo[(size_t)(kb + r) * N + nb + nq]);
      tile[r][nq] = g.x; tile[r][nq + 1] = g.y;
      tile[r][nq + 2] = g.z; tile[r][nq + 3] = g.w;
    }
    __syncthreads();
    const int n = t >> 1, kh = (t & 1) * 16;
    bf8 a0, a1, b0, b1;
#pragma unroll
    for (int e = 0; e < 16; ++e) {
      const float f = tile[kh + e][n];
      const short s1 = f2bf(f);
      const short s2 = f2bf(f - bf2f(s1));
      if (e < 8) { a0[e] = s1; b0[e] = s2; }
      else       { a1[e - 8] = s1; b1[e - 8] = s2; }
    }
    const size_t o = (size_t)(nb + n) * K + kb + kh;
    const size_t ls = (size_t)N * K;
    *reinterpret_cast<bf8*>(WoS + o) = a0;
    *reinterpret_cast<bf8*>(WoS + o + 8) = a1;
    *reinterpret_cast<bf8*>(WoS + o + ls) = b0;
    *reinterpret_cast<bf8*>(WoS + o + ls + 8) = b1;
  }
}

// ---------------------------------------------------------------- K1: qkv GEMM
// Fallback path: f32 VALU (R4-proven numerics).
__global__ __launch_bounds__(256) void qkv_gemm(
    const float* __restrict__ X, const float* __restrict__ W,
    float* __restrict__ Qf32, short* __restrict__ KF, short* __restrict__ VF) {
  __shared__ float As[16][132];
  __shared__ float Bs[16][132];
  const int t = threadIdx.x;
  const int n0 = blockIdx.x * 128;
  const int m0 = blockIdx.y * 128;
  const int ti = t >> 4, tj = t & 15;
  float acc[8][8] = {};
  for (int kt = 0; kt < 512; kt += 16) {
#pragma unroll
    for (int e = 0; e < 2; ++e) {
      int idx = e * 256 + t;
      int m = idx >> 2, kq = (idx & 3) << 2;
      const float4 g = *reinterpret_cast<const float4*>(
          &X[(size_t)(m0 + m) * 512 + kt + kq]);
      As[kq + 0][m] = g.x; As[kq + 1][m] = g.y;
      As[kq + 2][m] = g.z; As[kq + 3][m] = g.w;
    }
#pragma unroll
    for (int e = 0; e < 2; ++e) {
      int idx = e * 256 + t;
      int kk = idx >> 5, n4 = (idx & 31) << 2;
      *reinterpret_cast<float4*>(&Bs[kk][n4]) =
          *reinterpret_cast<const float4*>(&W[(size_t)(kt + kk) * 1536 + n0 + n4]);
    }
    __syncthreads();
#pragma unroll
    for (int kk = 0; kk < 16; ++kk) {
      const float4 A0 = *reinterpret_cast<const float4*>(&As[kk][ti * 8]);
      const float4 A1 = *reinterpret_cast<const float4*>(&As[kk][ti * 8 + 4]);
      const float4 B0 = *reinterpret_cast<const float4*>(&Bs[kk][tj * 8]);
      const float4 B1 = *reinterpret_cast<const float4*>(&Bs[kk][tj * 8 + 4]);
      const float a[8] = {A0.x, A0.y, A0.z, A0.w, A1.x, A1.y, A1.z, A1.w};
      const float b[8] = {B0.x, B0.y, B0.z, B0.w, B1.x, B1.y, B1.z, B1.w};
#pragma unroll
      for (int ii = 0; ii < 8; ++ii)
#pragma unroll
        for (int jj = 0; jj < 8; ++jj)
          acc[ii][jj] = fmaf(a[ii], b[jj], acc[ii][jj]);
    }
    __syncthreads();
  }
  const int part = n0 >> 9;     // 0=Q 1=K 2=V
  if (part == 0) {
#pragma unroll
    for (int ii = 0; ii < 8; ++ii) {
      const int r = m0 + ti * 8 + ii;
      const int bb = r >> 11, tt = r & 2047;
#pragma unroll
      for (int jj = 0; jj < 8; ++jj) {
        const int c = (n0 & 511) + tj * 8 + jj;
        const int h = c >> 6, d = c & 63;
        Qf32[(size_t)(bb * 8 + h) * 131072 + (size_t)tt * 64 + d] =
            acc[ii][jj] * 0.125f;
      }
    }
  } else if (part == 1) {
    const int cc0 = (n0 & 511) + tj * 8;
    const int h = cc0 >> 6, d0 = cc0 & 63;
    const int kk = d0 >> 5, lg = (d0 & 31) >> 3;   // j = d&7 == jj
#pragma unroll
    for (int ii = 0; ii < 8; ++ii) {
      const int r = m0 + ti * 8 + ii;
      const int bb = r >> 11, tt = r & 2047;
      const size_t base = (size_t)(bb * 8 + h) * 393216 +
                          (size_t)(tt >> 4) * 3072 + kk * 512 +
                          ((tt & 15) + 16 * lg) * 8;
      bf8 v1, v2, v3;
#pragma unroll
      for (int jj = 0; jj < 8; ++jj) {
        const float f = acc[ii][jj];
        const short s1 = f2bf(f);  const float r1 = f - bf2f(s1);
        const short s2 = f2bf(r1);
        const short s3 = f2bf(r1 - bf2f(s2));
        v1[jj] = s1; v2[jj] = s2; v3[jj] = s3;
      }
      *reinterpret_cast<bf8*>(KF + base)        = v1;
      *reinterpret_cast<bf8*>(KF + base + 1024) = v2;
      *reinterpret_cast<bf8*>(KF + base + 2048) = v3;
    }
  } else {
    const int t0r = m0 + ti * 8;                 // 8-aligned -> j = s&7 == ii
    const int bb = t0r >> 11, tt0 = t0r & 2047;
    const int cc = tt0 >> 5, lgs = (tt0 & 31) >> 3;
#pragma unroll
    for (int jj = 0; jj < 8; ++jj) {
      const int c = (n0 & 511) + tj * 8 + jj;
      const int h = c >> 6, dd = c & 63;
      bf8 pv;
#pragma unroll
      for (int ii = 0; ii < 8; ++ii) pv[ii] = f2bf(acc[ii][jj]);
      *reinterpret_cast<bf8*>(VF + (size_t)(bb * 8 + h) * 131072 +
                              cc * 2048 + (dd >> 4) * 512 +
                              ((dd & 15) + 16 * lgs) * 8) = pv;
    }
  }
}

// ---------------------------------------- K1': qkv GEMM via MFMA (main path)
// A = XS [3][8192][512], B = WqS [3][1536][512]; 6-term ladder, LV=3 STATIC.
// Accs round-trip through LDS scratch so the proven (ti,tj) epilogue is reused.
__global__ __launch_bounds__(256) void qkv_mfma(
    const short* __restrict__ XS, const short* __restrict__ WqS,
    float* __restrict__ Qf32, short* __restrict__ KF, short* __restrict__ VF) {
  extern __shared__ char sm_[];
  short* As = (short*)sm_;                 // [3][128][40] bf16
  short* Bs = (short*)(sm_ + 30720);       // [3][128][40] bf16
  float* SC = (float*)sm_;                 // [128][132] f32 (after k-loop)
  const int t = threadIdx.x;
  const int w = t >> 6, lane = t & 63;
  const int lq = lane & 15, lg = lane >> 4;
  const int wr = w >> 1, wc = w & 1;
  const int n0 = blockIdx.x * 128, m0 = blockIdx.y * 128;
  const int part = n0 >> 9;                // 0=Q 1=K 2=V
  f32x4 acc[4][4];
#pragma unroll
  for (int i = 0; i < 4; ++i)
#pragma unroll
    for (int j2 = 0; j2 < 4; ++j2) acc[i][j2] = (f32x4){0.f, 0.f, 0.f, 0.f};
  const int sr = t >> 1, sh = (t & 1) * 16;
  for (int k0 = 0; k0 < 512; k0 += 32) {
#pragma unroll
    for (int lev = 0; lev < 3; ++lev) {
      const size_t xa = (size_t)lev * 4194304 + (size_t)(m0 + sr) * 512 + k0 + sh;
      *reinterpret_cast<bf8*>(&As[(lev * 128 + sr) * 40 + sh])     =
          *reinterpret_cast<const bf8*>(XS + xa);
      *reinterpret_cast<bf8*>(&As[(lev * 128 + sr) * 40 + sh + 8]) =
          *reinterpret_cast<const bf8*>(XS + xa + 8);
      const size_t wa = (size_t)lev * 786432 + (size_t)(n0 + sr) * 512 + k0 + sh;
      *reinterpret_cast<bf8*>(&Bs[(lev * 128 + sr) * 40 + sh])     =
          *reinterpret_cast<const bf8*>(WqS + wa);
      *reinterpret_cast<bf8*>(&Bs[(lev * 128 + sr) * 40 + sh + 8]) =
          *reinterpret_cast<const bf8*>(WqS + wa + 8);
    }
    __syncthreads();
    bf8 bfr[4][3];
#pragma unroll
    for (int i = 0; i < 4; ++i)
#pragma unroll
      for (int lev = 0; lev < 3; ++lev)
        bfr[i][lev] = *reinterpret_cast<const bf8*>(
            &Bs[(lev * 128 + wc * 64 + i * 16 + lq) * 40 + lg * 8]);
#pragma unroll
    for (int mi = 0; mi < 4; ++mi) {
      bf8 af0 = *reinterpret_cast<const bf8*>(
          &As[(0 * 128 + wr * 64 + mi * 16 + lq) * 40 + lg * 8]);
      bf8 af1 = *reinterpret_cast<const bf8*>(
          &As[(1 * 128 + wr * 64 + mi * 16 + lq) * 40 + lg * 8]);
      bf8 af2 = *reinterpret_cast<const bf8*>(
          &As[(2 * 128 + wr * 64 + mi * 16 + lq) * 40 + lg * 8]);
#pragma unroll
      for (int ni = 0; ni < 4; ++ni) {
        MFMA16(af0, bfr[ni][0], acc[mi][ni]);       // 1
        MFMA16(af0, bfr[ni][1], acc[mi][ni]);       // 2^-8
        MFMA16(af1, bfr[ni][0], acc[mi][ni]);       // 2^-8
        MFMA16(af1, bfr[ni][1], acc[mi][ni]);       // 2^-16
        MFMA16(af0, bfr[ni][2], acc[mi][ni]);       // 2^-16
        MFMA16(af2, bfr[ni][0], acc[mi][ni]);       // 2^-16
      }
    }
    __syncthreads();
  }
  // dump accs to scratch in (m,n) order
#pragma unroll
  for (int mi = 0; mi < 4; ++mi)
#pragma unroll
    for (int ni = 0; ni < 4; ++ni)
#pragma unroll
      for (int r = 0; r < 4; ++r)
        SC[(wr * 64 + mi * 16 + lg * 4 + r) * 132 + wc * 64 + ni * 16 + lq] =
            acc[mi][ni][r];
  __syncthreads();
  // epilogue: verbatim qkv_gemm scatter, accL re-read in (ti,tj) 8x8 order
  const int ti = t >> 4, tj = t & 15;
  float accL[8][8];
#pragma unroll
  for (int ii = 0; ii < 8; ++ii) {
    const float4 c0 = *reinterpret_cast<const float4*>(&SC[(ti * 8 + ii) * 132 + tj * 8]);
    const float4 c1 = *reinterpret_cast<const float4*>(&SC[(ti * 8 + ii) * 132 + tj * 8 + 4]);
    accL[ii][0] = c0.x; accL[ii][1] = c0.y; accL[ii][2] = c0.z; accL[ii][3] = c0.w;
    accL[ii][4] = c1.x; accL[ii][5] = c1.y; accL[ii][6] = c1.z; accL[ii][7] = c1.w;
  }
  if (part == 0) {
#pragma unroll
    for (int ii = 0; ii < 8; ++ii) {
      const int r = m0 + ti * 8 + ii;
      const int bb = r >> 11, tt = r & 2047;
#pragma unroll
      for (int jj = 0; jj < 8; ++jj) {
        const int c = (n0 & 511) + tj * 8 + jj;
        const int h = c >> 6, d = c & 63;
        Qf32[(size_t)(bb * 8 + h) * 131072 + (size_t)tt * 64 + d] =
            accL[ii][jj] * 0.125f;
      }
    }
  } else if (part == 1) {
    const int cc0 = (n0 & 511) + tj * 8;
    const int h = cc0 >> 6, d0 = cc0 & 63;
    const int kk = d0 >> 5, lg2 = (d0 & 31) >> 3;   // j = d&7 == jj
#pragma unroll
    for (int ii = 0; ii < 8; ++ii) {
      const int r = m0 + ti * 8 + ii;
      const int bb = r >> 11, tt = r & 2047;
      const size_t base = (size_t)(bb * 8 + h) * 393216 +
                          (size_t)(tt >> 4) * 3072 + kk * 512 +
                          ((tt & 15) + 16 * lg2) * 8;
      bf8 v1, v2, v3;
#pragma unroll
      for (int jj = 0; jj < 8; ++jj) {
        const float f = accL[ii][jj];
        const short s1 = f2bf(f);  const float r1 = f - bf2f(s1);
        const short s2 = f2bf(r1);
        const short s3 = f2bf(r1 - bf2f(s2));
        v1[jj] = s1; v2[jj] = s2; v3[jj] = s3;
      }
      *reinterpret_cast<bf8*>(KF + base)        = v1;
      *reinterpret_cast<bf8*>(KF + base + 1024) = v2;
      *reinterpret_cast<bf8*>(KF + base + 2048) = v3;
    }
  } else {
    const int t0r = m0 + ti * 8;                 // 8-aligned -> j = s&7 == ii
    const int bb = t0r >> 11, tt0 = t0r & 2047;
    const int cc = tt0 >> 5, lgs = (tt0 & 31) >> 3;
#pragma unroll
    for (int jj = 0; jj < 8; ++jj) {
      const int c = (n0 & 511) + tj * 8 + jj;
      const int h = c >> 6, dd = c & 63;
      bf8 pv;
#pragma unroll
      for (int ii = 0; ii < 8; ++ii) pv[ii] = f2bf(accL[ii][jj]);
      *reinterpret_cast<bf8*>(VF + (size_t)(bb * 8 + h) * 131072 +
                              cc * 2048 + (dd >> 4) * 512 +
                              ((dd & 15) + 16 * lgs) * 8) = pv;
    }
  }
}

// ------------------------------------------------------------- K3: out proj GEMM
__global__ __launch_bounds__(256) void out_mfma(
    const short* __restrict__ HOS, const short* __restrict__ WoS,
    float* __restrict__ OUT) {
  __shared__ short As[2][128][40];
  __shared__ short Bs[2][128][40];
  const int t = threadIdx.x;
  const int w = t >> 6, lane = t & 63;
  const int lq = lane & 15, lg = lane >> 4;
  const int wr = w >> 1, wc = w & 1;
  const int n0 = blockIdx.x * 128, m0 = blockIdx.y * 128;
  f32x4 acc[4][4];
#pragma unroll
  for (int i = 0; i < 4; ++i)
#pragma unroll
    for (int j2 = 0; j2 < 4; ++j2) acc[i][j2] = (f32x4){0.f, 0.f, 0.f, 0.f};
  const int sm = t >> 1, sh = (t & 1) * 16;
  for (int k0 = 0; k0 < 512; k0 += 32) {
#pragma unroll
    for (int lev = 0; lev < 2; ++lev) {
      const size_t xa = (size_t)lev * 4194304 + (size_t)(m0 + sm) * 512 + k0 + sh;
      *reinterpret_cast<bf8*>(&As[lev][sm][sh])     = *reinterpret_cast<const bf8*>(HOS + xa);
      *reinterpret_cast<bf8*>(&As[lev][sm][sh + 8]) = *reinterpret_cast<const bf8*>(HOS + xa + 8);
      const size_t wa = (size_t)lev * 262144 + (size_t)(n0 + sm) * 512 + k0 + sh;
      *reinterpret_cast<bf8*>(&Bs[lev][sm][sh])     = *reinterpret_cast<const bf8*>(WoS + wa);
      *reinterpret_cast<bf8*>(&Bs[lev][sm][sh + 8]) = *reinterpret_cast<const bf8*>(WoS + wa + 8);
    }
    __syncthreads();
    bf8 af[4][2], bfr[4][2];
#pragma unroll
    for (int i = 0; i < 4; ++i)
#pragma unroll
      for (int lev = 0; lev < 2; ++lev) {
        af[i][lev]  = *reinterpret_cast<const bf8*>(&As[lev][wr * 64 + i * 16 + lq][lg * 8]);
        bfr[i][lev] = *reinterpret_cast<const bf8*>(&Bs[lev][wc * 64 + i * 16 + lq][lg * 8]);
      }
#pragma unroll
    for (int mi = 0; mi < 4; ++mi)
#pragma unroll
      for (int ni = 0; ni < 4; ++ni) {
        MFMA16(af[mi][0], bfr[ni][0], acc[mi][ni]);
        MFMA16(af[mi][0], bfr[ni][1], acc[mi][ni]);
        MFMA16(af[mi][1], bfr[ni][0], acc[mi][ni]);
      }
    __syncthreads();
  }
#pragma unroll
  for (int mi = 0; mi < 4; ++mi)
#pragma unroll
    for (int r = 0; r < 4; ++r) {
      const int m = m0 + wr * 64 + mi * 16 + lg * 4 + r;
#pragma unroll
      for (int ni = 0; ni < 4; ++ni)
        OUT[(size_t)m * 512 + n0 + wc * 64 + ni * 16 + lq] = acc[mi][ni][r];
    }
}

// ---------------------------------------------------------------- K2: attention
// R15's kernel verbatim (the fastest measured attn: 277.7 us).
// 512 threads = 8 waves; 16 distinct q-rows (row = lq); two-half logit staging
// through a 64 KB region + 8 KB park = 72 KB -> 2 blocks/CU.
__global__ __launch_bounds__(512, 4) void attn_mfma(
    const float* __restrict__ Qf32, const short* __restrict__ KF,
    const short* __restrict__ VF, const float* __restrict__ alpha,
    short* __restrict__ HOS) {
  extern __shared__ char lds[];
  const int tid = threadIdx.x;
  const int w = tid >> 6, lane = tid & 63;      // w in [0,8)
  const int lq = lane & 15, lg = lane >> 4;
  const int row = lq;                            // 16 distinct rows

  // XCD swizzle: 4096 blocks, 512/XCD = 4 bh x 128 qb
  const int flat = blockIdx.x + (int)gridDim.x * blockIdx.y;
  const int xcd = flat & 7, idx = flat >> 3;
  const int bh = xcd * 4 + (idx >> 7);
  const int qb = idx & 127;
  const int b = bh >> 3, h = bh & 7;
  const int q0 = qb * 16;

  const float gate = 1.0f / (1.0f + __expf(-alpha[h]));
  const int key = row & 7;                       // row's swizzle key

  // Q fragments: load f32 row q0+row, split 3-level in-register
  bf8 qf[3][2];
  {
    const float* qp = Qf32 + (size_t)bh * 131072 + (size_t)(q0 + row) * 64 + lg * 8;
#pragma unroll
    for (int kk = 0; kk < 2; ++kk) {
      const float4 g0 = *reinterpret_cast<const float4*>(qp + kk * 32);
      const float4 g1 = *reinterpret_cast<const float4*>(qp + kk * 32 + 4);
      const float v[8] = {g0.x, g0.y, g0.z, g0.w, g1.x, g1.y, g1.z, g1.w};
#pragma unroll
      for (int e = 0; e < 8; ++e) {
        const short s1 = f2bf(v[e]);  const float r1 = v[e] - bf2f(s1);
        const short s2 = f2bf(r1);
        const short s3 = f2bf(r1 - bf2f(s2));
        qf[0][kk][e] = s1; qf[1][kk][e] = s2; qf[2][kk][e] = s3;
      }
    }
  }

  auto ldk = [&](int t, bf8 (&dst)[3][2]) {
    const short* p = KF + (size_t)(bh * 128 + t) * 3072 + lane * 8;
    dst[0][0] = *reinterpret_cast<const bf8*>(p);
    dst[0][1] = *reinterpret_cast<const bf8*>(p + 512);
    dst[1][0] = *reinterpret_cast<const bf8*>(p + 1024);
    dst[1][1] = *reinterpret_cast<const bf8*>(p + 1536);
    dst[2][0] = *reinterpret_cast<const bf8*>(p + 2048);
    dst[2][1] = *reinterpret_cast<const bf8*>(p + 2560);
  };
  // write uses the tile's LOCAL slot (t & 63): both s-halves share the region
  auto qk = [&](bf8 (&kf)[3][2], int t) {
    f32x4 c0 = {0.f,0.f,0.f,0.f}, c1 = {0.f,0.f,0.f,0.f}, c2 = {0.f,0.f,0.f,0.f};
#pragma unroll
    for (int kk = 0; kk < 2; ++kk) {
      MFMA16(kf[0][kk], qf[0][kk], c0);   // 1
      MFMA16(kf[0][kk], qf[1][kk], c1);   // 2^-8
      MFMA16(kf[1][kk], qf[0][kk], c1);   // 2^-8
      MFMA16(kf[1][kk], qf[1][kk], c2);   // 2^-16
      MFMA16(kf[0][kk], qf[2][kk], c2);   // 2^-16
      MFMA16(kf[2][kk], qf[0][kk], c2);   // 2^-16
    }
    const f32x4 c = (c0 + c1) + c2;
    *reinterpret_cast<f32x4*>(
        lds + row * 4096 + ((((((t & 63) << 2)) + lg) ^ key) << 4)) = c;
  };

  float av[2][32];
  float lm[2] = {-3.402823466e+38f, -3.402823466e+38f};

  bf8 ka[3][2], kb[3][2];
  // ---- P1a: s-half A, tiles w+8j, j=0..7 (8 tiles/wave)
  ldk(w, ka);
#pragma unroll
  for (int j = 0; j < 8; j += 2) {
    const int t0 = w + 8 * j;
    ldk(t0 + 8, kb);
    qk(ka, t0);
    if (j + 2 < 8) ldk(t0 + 16, ka);
    qk(kb, t0 + 8);
  }
  ldk(w + 64, ka);     // half-B prologue; latency spans the next two phases
  __syncthreads();

  // ---- loadA: wave w pulls half-A logits of rows w and w+8 into registers
#pragma unroll
  for (int rr = 0; rr < 2; ++rr) {
    const char* rowb = lds + (w + 8 * rr) * 4096;
#pragma unroll
    for (int jj = 0; jj < 4; ++jj) {
      const f32x4 v = *reinterpret_cast<const f32x4*>(rowb + ((lane + 64 * jj) << 4));
#pragma unroll
      for (int e = 0; e < 4; ++e) {
        av[rr][jj * 4 + e] = v[e];
        lm[rr] = fmaxf(lm[rr], v[e]);
      }
    }
  }
  __syncthreads();

  // ---- P1b: s-half B, tiles 64 + w+8j, overwrites the same region
#pragma unroll
  for (int j = 0; j < 8; j += 2) {
    const int t0 = 64 + w + 8 * j;
    ldk(t0 + 8, kb);
    qk(ka, t0);
    if (j + 2 < 8) ldk(t0 + 16, ka);
    qk(kb, t0 + 8);
  }
  __syncthreads();

  // ---- loadB + P2 x2 rows + weights (overwrite dead logit region)
  const int dt3 = w & 3, cg = w >> 2;            // P3 assignment
  bf8 va1, vb1;
  auto ldv1 = [&](int cc, bf8& dst) {
    dst = *reinterpret_cast<const bf8*>(
        VF + (size_t)(bh * 64 + cc) * 2048 + dt3 * 512 + lane * 8);
  };
  {
#pragma unroll
    for (int rr = 0; rr < 2; ++rr) {
      const char* rowb = lds + (w + 8 * rr) * 4096;
#pragma unroll
      for (int jj = 4; jj < 8; ++jj) {
        const f32x4 v = *reinterpret_cast<const f32x4*>(
            rowb + ((lane + 64 * (jj - 4)) << 4));
#pragma unroll
        for (int e = 0; e < 4; ++e) {
          av[rr][jj * 4 + e] = v[e];
          lm[rr] = fmaxf(lm[rr], v[e]);
        }
      }
    }
    ldv1(cg * 32, va1);                          // V prefetch under P2 math
#pragma unroll
    for (int rr = 0; rr < 2; ++rr) {
      const int q = w + 8 * rr;
      const int rkey = q & 7;
      // m = global max; g0 = min of per-lane maxima -> cnt(>=g0) >= 64.
      float m = lm[rr], g0 = lm[rr];
#pragma unroll
      for (int off = 32; off; off >>= 1) {
        m = fmaxf(m, __shfl_xor(m, off));
        g0 = fminf(g0, __shfl_xor(g0, off));
      }
      // invariant: cnt(>= lo) >= 64; cnt(>= hi) < 64 (generic case)
      float lo = g0, hi = m;
      for (int it = 0; it < 64; ++it) {
        const float mid = 0.5f * (lo + hi);
        if (!(mid > lo && mid < hi)) break;      // bracket collapsed (ties)
        int cnt = 0;
#pragma unroll
        for (int j = 0; j < 32; ++j)
          cnt += (int)__popcll(__ballot(av[rr][j] >= mid));
        if (cnt >= 64) {
          lo = mid;
          if (cnt == 64) break;                  // gap hit: exactly top-64
        } else {
          hi = mid;
        }
      }
      const float thr = lo;
      float dsum = 0.f, ssum = 0.f;
#pragma unroll
      for (int j = 0; j < 32; ++j) {
        const float e = __expf(av[rr][j] - m);
        dsum += e;
        ssum += (av[rr][j] >= thr) ? e : 0.f;
      }
#pragma unroll
      for (int off = 32; off; off >>= 1) {
        dsum += __shfl_xor(dsum, off);
        ssum += __shfl_xor(ssum, off);
      }
      const float dinv = gate / dsum;
      const float sinv = (1.0f - gate) / ssum;
#pragma unroll
      for (int jj = 0; jj < 8; ++jj) {
        const int p = lane + 64 * jj;
        const int f = p ^ rkey;
        float wv[4];
#pragma unroll
        for (int e2 = 0; e2 < 4; ++e2) {
          const float a = av[rr][jj * 4 + e2];
          wv[e2] = __expf(a - m) * (dinv + ((a >= thr) ? sinv : 0.f));
        }
        uint2 pk;
        pk.x = pack_bf16x2(wv[0], wv[1]);
        pk.y = pack_bf16x2(wv[2], wv[3]);
        *reinterpret_cast<uint2*>(
            lds + q * 4096 + ((((f >> 1) ^ rkey) << 4) + ((f & 1) << 3))) = pk;
      }
    }
  }
  __syncthreads();

  // ---- P3: wave w owns d-tile dt3 over 32 s-chunks cc = cg*32 + j.
  f32x4 o = {0.f, 0.f, 0.f, 0.f};
  {
    auto pv1 = [&](bf8 vv, int cc) {
      const bf8 pa = *reinterpret_cast<const bf8*>(
          lds + row * 4096 + ((((cc << 2) + lg) ^ key) << 4));
      MFMA16(pa, vv, o);
    };
#pragma unroll
    for (int j = 0; j < 32; j += 2) {
      const int cc = cg * 32 + j;
      ldv1(cc + 1, vb1);
      pv1(va1, cc);
      if (j + 2 < 32) ldv1(cc + 2, va1);
      pv1(vb1, cc + 1);
    }
  }
  // park: wave w -> slot w (8 KB region at 64 KB)
  {
    char* pb = lds + 65536 + (w << 10);
#pragma unroll
    for (int r = 0; r < 4; ++r)
      *reinterpret_cast<float*>(pb + (((lg * 4 + r) * 16 + lq) << 2)) = o[r];
  }
  __syncthreads();
  // reduce 2 partials (waves cg*4 + dt), write HOS. 512 thr x 2 passes.
  {
#pragma unroll
    for (int p = 0; p < 2; ++p) {
      const int q = (tid >> 6) + 8 * p, d = tid & 63;
      const int dt2 = d >> 4;
      const float s =
          *reinterpret_cast<const float*>(
              lds + 65536 + (dt2 << 10) + ((q * 16 + (d & 15)) << 2)) +
          *reinterpret_cast<const float*>(
              lds + 65536 + ((4 + dt2) << 10) + ((q * 16 + (d & 15)) << 2));
      const size_t o2 = (size_t)(b * TSEQ + q0 + q) * 512 + h * 64 + d;
      const short s1 = f2bf(s);
      HOS[o2] = s1;
      HOS[o2 + 4194304] = f2bf(s - bf2f(s1));
    }
  }
}

// ------------------------------------------------------------------- launcher
extern "C" void kernel_launch(void* const* d_in, const int* in_sizes, int n_in,
                              void* d_out, int out_size, void* d_ws, size_t ws_size,
                              hipStream_t stream) {
  const float* x     = (const float*)d_in[0];
  const float* Wqkv  = (const float*)d_in[1];
  const float* Wout  = (const float*)d_in[2];
  const float* alpha = (const float*)d_in[3];
  float* out = (float*)d_out;

  float* Qf32 = (float*)d_ws;
  short* S16  = (short*)d_ws;
  short* KF   = S16 + 8388608;
  short* VF   = S16 + 20971520;
  short* HOS  = S16 + 25165824;
  short* WoS  = S16 + 33554432;
  short* WqS  = S16 + 34078720;   // 3 x 1536 x 512
  short* XSp  = S16 + 36438016;   // 3 x 8192 x 512

  const int attn_lds = 73728;     // 64 KB logits/weights + 8 KB park
  (void)hipFuncSetAttribute((const void*)attn_mfma,
                            hipFuncAttributeMaxDynamicSharedMemorySize, attn_lds);

  const bool big = ws_size >= (size_t)98041856;
  if (big) {
    prep_fused<<<2304, 256, 0, stream>>>(x, Wqkv, Wout, XSp, WqS, WoS);
    const int qkv_lds = 67584;
    (void)hipFuncSetAttribute((const void*)qkv_mfma,
                              hipFuncAttributeMaxDynamicSharedMemorySize, qkv_lds);
    qkv_mfma<<<dim3(12, 64), 256, qkv_lds, stream>>>(XSp, WqS, Qf32, KF, VF);
  } else {
    transpose_split<<<dim3(4, 16), 256, 0, stream>>>(Wout, WoS, 512, 512);
    qkv_gemm<<<dim3(12, 64), 256, 0, stream>>>(x, Wqkv, Qf32, KF, VF);
  }
  attn_mfma<<<dim3(128, 32), 512, attn_lds, stream>>>(Qf32, KF, VF, alpha, HOS);
  out_mfma<<<dim3(4, 64), 256, 0, stream>>>(HOS, WoS, out);
}